// Round 9
// baseline (242.479 us; speedup 1.0000x reference)
//
#include <hip/hip_runtime.h>
#include <hip/hip_bf16.h>

// Problem constants
#define BATCH   4096
#define SDIM    512
#define ADIM    64
#define IDIM    577           // 512 + 64 + 1
#define KP2     640           // IDIM padded to 10*64
#define NKT64   10            // K-tiles of 64
#define HDIM    2048
#define ZDIM    8192          // 4*HDIM
#define BUFE    (128 * 64)    // LDS elems per A buffer (16KB)

typedef __attribute__((ext_vector_type(8))) __bf16 bf16x8;
typedef __attribute__((ext_vector_type(4))) float  accx4;

// ---------------------------------------------------------------------------
// Fused setup kernel (unchanged — proven). Role by flat blockIdx:
//   [0,1280)     transpose Wx: 64k x 64n tiles -> wxt [8192][640]bf16
//   [1280,1536)  zh partials: zh_w[ky][n] = sum_{k in ky*256..+256} h*Wh
//   [1536,5632)  prep xb rows: bf16 [s|a|r|0pad] (4096 x 640)
//   [5632,5760)  transpose Wa [2048,64]f32 -> waT [64][2048]bf16
// ---------------------------------------------------------------------------
__global__ __launch_bounds__(256) void setup_kernel(
    const float* __restrict__ s, const float* __restrict__ a_prev,
    const float* __restrict__ r_prev, const float* __restrict__ h,
    const float* __restrict__ wx, const float* __restrict__ wh,
    const float* __restrict__ wa,
    __hip_bfloat16* __restrict__ xb, __hip_bfloat16* __restrict__ wxt,
    __hip_bfloat16* __restrict__ waT, float* __restrict__ zh_w)
{
    __shared__ float stile[64 * 65];        // 16.6KB, stride 65 (conflict-free)
    const int bid = blockIdx.x;
    const int t = threadIdx.x;

    if (bid < 1280) {                       // ---- transpose Wx (64k x 64n)
        const int kt2 = bid >> 7;           // 0..9
        const int nt  = bid & 127;          // 0..127
        const int c4  = t & 15;             // float4 column
        const int rr  = t >> 4;             // 0..15
#pragma unroll
        for (int i = 0; i < 4; ++i) {
            const int r = rr + i * 16;      // k within tile
            const int k = kt2 * 64 + r;
            float4 v = (k < IDIM)
                ? *(const float4*)(wx + (size_t)k * ZDIM + nt * 64 + c4 * 4)
                : float4{0.f, 0.f, 0.f, 0.f};
            *(float4*)(stile + r * 65 + c4 * 4) = v;
        }
        __syncthreads();
        const int ch = t & 7;               // k-chunk
#pragma unroll
        for (int i = 0; i < 2; ++i) {
            const int nr = (t >> 3) + i * 32;   // n-row 0..63
            bf16x8 w8;
#pragma unroll
            for (int j = 0; j < 8; ++j)
                w8[j] = (__bf16)stile[(ch * 8 + j) * 65 + nr];
            *(bf16x8*)(wxt + (size_t)(nt * 64 + nr) * KP2 + kt2 * 64 + ch * 8)
                = w8;
        }
    } else if (bid < 1536) {                // ---- zh partials (8 k-splits)
        const int zb = bid - 1280;
        const int nb = zb & 31, ky = zb >> 5;       // nb 0..31, ky 0..7
        const int n  = nb * 256 + t;
        const float* hp  = h + ky * 256;
        const float* whp = wh + (size_t)ky * 256 * ZDIM + n;
        float p = 0.0f;
#pragma unroll 16
        for (int kk = 0; kk < 256; ++kk)
            p = fmaf(hp[kk], whp[(size_t)kk * ZDIM], p);
        zh_w[ky * ZDIM + n] = p;
    } else if (bid < 5632) {                // ---- prep xb row
        const int row = bid - 1536;
        const float* srow = s + (size_t)row * SDIM;
        const float* arow = a_prev + (size_t)row * ADIM;
        __hip_bfloat16* xrow = xb + (size_t)row * KP2;
        for (int c = t; c < KP2; c += 256) {
            float v;
            if (c < SDIM)        v = srow[c];
            else if (c < 576)    v = arow[c - SDIM];
            else if (c == 576)   v = r_prev[row];
            else                 v = 0.0f;
            xrow[c] = __float2bfloat16(v);
        }
    } else {                                // ---- transpose Wa (32k x 32a)
        const int wb = bid - 5632;
        const int kt = wb >> 1, at = wb & 1;
        const int c  = t & 31, r0 = t >> 5;
#pragma unroll
        for (int i = 0; i < 4; ++i) {
            int r = r0 + i * 8;             // k within tile
            stile[r * 33 + c] = wa[(size_t)(kt * 32 + r) * ADIM + at * 32 + c];
        }
        __syncthreads();
#pragma unroll
        for (int i = 0; i < 4; ++i) {
            int r = r0 + i * 8;             // action within tile
            waT[(size_t)(at * 32 + r) * HDIM + kt * 32 + c] =
                __float2bfloat16(stile[c * 33 + r]);
        }
    }
}

// ---------------------------------------------------------------------------
// Main bf16 MFMA GEMM + fused LSTM epilogue.
// Structure = R7's PROVEN skeleton (A double-buffered in LDS, 128B rows,
// slot = chunk ^ (row&7) swizzle — HW-verified 0 conflicts; one barrier per
// K-tile with A-prefetch issued before compute), with ONE change:
// B is no longer staged in LDS — each wave loads its 8 B-fragments (4 gates
// x 2 half-k) DIRECT to registers from L2-resident wxt (head_kernel's
// proven pattern), prefetched one K-tile ahead. This removes half the LDS
// traffic and halves LDS footprint (64KB -> 32KB => more blocks/CU).
// NOTE (R8 lesson): global_load_lds REQUIRES the __syncthreads barrier for
// its vmcnt drain — never remove it.
// ---------------------------------------------------------------------------
__device__ __forceinline__ float sigmoid_f(float x) {
    return 1.0f / (1.0f + __expf(-x));
}
__device__ __forceinline__ float tanh_f(float x) {
    return 1.0f - 2.0f / (1.0f + __expf(2.0f * x));
}

__global__ __launch_bounds__(256, 2) void lstm_gemm(
    const __hip_bfloat16* __restrict__ xb,   // [4096][640] bf16
    const __hip_bfloat16* __restrict__ wxt,  // [8192][640] bf16 (n-major)
    const float* __restrict__ zh_w,          // [8][8192] k-split partials
    const float* __restrict__ bh,            // [8192]
    const float* __restrict__ cvec,          // [2048]
    __hip_bfloat16* __restrict__ hout)       // [4096][2048] bf16
{
    __shared__ __bf16 smA[2 * BUFE];   // 32KB  [buf][row][k-chunk swizzled]
    const int t    = threadIdx.x;
    const int lane = t & 63;
    const int wid  = t >> 6;
    const int m0   = blockIdx.x * 128;
    const int n0   = blockIdx.y * 32;
    const int wm   = wid >> 1, wn = wid & 1;
    const int fl15 = lane & 15;
    const int fhi  = lane >> 4;        // 0..3

    accx4 acc[4][4] = {};              // [gate][rowtile]

    // ---- A staging addresses (R7-proven, loop-invariant) ----
    const int srow = lane >> 3;        // 0..7
    const int slot = lane & 7;
    const int cch  = slot ^ srow;      // swizzled source chunk (lane-const)
    const __bf16* gA[4]; int lofs[4];
#pragma unroll
    for (int i = 0; i < 4; ++i) {
        const int r = wid * 32 + i * 8 + srow;               // 0..127
        gA[i] = (const __bf16*)xb + (size_t)(m0 + r) * KP2 + cch * 8;
        lofs[i] = (wid * 32 + i * 8) * 64;                   // wave-uniform
    }

    // ---- B row pointers: gate g, h-unit (n0 + wn*16 + fl15) ----
    const __bf16* gB[4];
#pragma unroll
    for (int g = 0; g < 4; ++g)
        gB[g] = (const __bf16*)wxt +
            (size_t)(g * HDIM + n0 + wn * 16 + fl15) * KP2 + fhi * 8;

    auto stageA = [&](int tile, int p) {
        const int ko = tile * 64;
        const int po = p * BUFE;
#pragma unroll
        for (int i = 0; i < 4; ++i)
            __builtin_amdgcn_global_load_lds(
                (const __attribute__((address_space(1))) void*)(gA[i] + ko),
                (__attribute__((address_space(3))) void*)(smA + po + lofs[i]),
                16, 0, 0);
    };

    bf16x8 bcur[4][2], bnext[4][2];
    auto loadB = [&](int tile, bf16x8 (&b)[4][2]) {
        const int ko = tile * 64;
#pragma unroll
        for (int g = 0; g < 4; ++g)
#pragma unroll
            for (int hf = 0; hf < 2; ++hf)
                b[g][hf] = *(const bf16x8*)(gB[g] + ko + hf * 32);
    };

    stageA(0, 0);
    loadB(0, bcur);
    __syncthreads();                   // A tile 0 landed (vmcnt drain)

#pragma unroll
    for (int kt = 0; kt < NKT64; ++kt) {
        if (kt < NKT64 - 1) {          // prefetch next tile FIRST
            stageA(kt + 1, (kt + 1) & 1);
            loadB(kt + 1, bnext);
        }
        const int po = (kt & 1) * BUFE;
#pragma unroll
        for (int hf = 0; hf < 2; ++hf) {
            const int sl = ((hf * 4 + fhi) ^ (fl15 & 7)) * 8;  // de-swizzle
            bf16x8 af[4];
#pragma unroll
            for (int rt = 0; rt < 4; ++rt)
                af[rt] = *(const bf16x8*)(smA + po +
                    (wm * 64 + rt * 16 + fl15) * 64 + sl);
#pragma unroll
            for (int g = 0; g < 4; ++g)
#pragma unroll
                for (int rt = 0; rt < 4; ++rt)
                    acc[g][rt] = __builtin_amdgcn_mfma_f32_16x16x32_bf16(
                        af[rt], bcur[g][hf], acc[g][rt], 0, 0, 0);
        }
        if (kt < NKT64 - 1) {
            __syncthreads();           // next A tile landed; buf consumed
#pragma unroll
            for (int g = 0; g < 4; ++g)
#pragma unroll
                for (int hf = 0; hf < 2; ++hf)
                    bcur[g][hf] = bnext[g][hf];
        }
    }

    // Epilogue. C/D layout: col=lane&15, row=(lane>>4)*4+reg (m89/m91).
    // zh partial-sum folded in (R5-proven): 4 gates x (bh + 8 partials).
    const int colg = n0 + wn * 16 + fl15;        // h-unit index
    float zsum[4];
#pragma unroll
    for (int g = 0; g < 4; ++g) {
        float z = bh[g * HDIM + colg];
#pragma unroll
        for (int j = 0; j < 8; ++j)
            z += zh_w[j * ZDIM + g * HDIM + colg];
        zsum[g] = z;
    }
    const float cv = cvec[colg];
#pragma unroll
    for (int rt = 0; rt < 4; ++rt) {
#pragma unroll
        for (int r = 0; r < 4; ++r) {
            const int row = m0 + wm * 64 + rt * 16 + (fhi << 2) + r;
            const float zi = acc[0][rt][r] + zsum[0];
            const float zf = acc[1][rt][r] + zsum[1];
            const float zg = acc[2][rt][r] + zsum[2];
            const float zo = acc[3][rt][r] + zsum[3];
            const float cn = sigmoid_f(zf) * cv + sigmoid_f(zi) * tanh_f(zg);
            const float hn = sigmoid_f(zo) * tanh_f(cn);
            hout[(size_t)row * HDIM + colg] = __float2bfloat16(hn);
        }
    }
}

// ---------------------------------------------------------------------------
// Policy+value head v3 (unchanged — proven). Block = 16 rows, 512 threads.
// ---------------------------------------------------------------------------
__global__ __launch_bounds__(512) void head_kernel(
    const __hip_bfloat16* __restrict__ hnew,  // [4096][2048] bf16
    const __hip_bfloat16* __restrict__ waT,   // [64][2048] bf16
    const float* __restrict__ wv,             // [2048] f32
    const float* __restrict__ ba, const float* __restrict__ bv,
    float* __restrict__ probs, float* __restrict__ vout)
{
    __shared__ float lg[8][16][68];    // 34.8KB partial logits
    __shared__ float vpart[8][16];
    const int t    = threadIdx.x;
    const int lane = t & 63;
    const int w    = t >> 6;           // k-eighth 0..7
    const int r0   = blockIdx.x * 16;
    const int fl15 = lane & 15, fhi = lane >> 4;
    const int k0   = w * 256;

    const __bf16* arow = (const __bf16*)hnew +
        (size_t)(r0 + fl15) * HDIM + k0 + fhi * 8;
    const __bf16* brow = (const __bf16*)waT +
        (size_t)fl15 * HDIM + k0 + fhi * 8;
    const float* wvp = wv + k0 + fhi * 8;

    accx4 acc[4] = {};
    float va0 = 0.f, va1 = 0.f;
#pragma unroll
    for (int kk = 0; kk < 256; kk += 32) {
        bf16x8 af = *(const bf16x8*)(arow + kk);
#pragma unroll
        for (int a = 0; a < 4; ++a) {
            bf16x8 bf = *(const bf16x8*)(brow + (size_t)a * 16 * HDIM + kk);
            acc[a] = __builtin_amdgcn_mfma_f32_16x16x32_bf16(
                af, bf, acc[a], 0, 0, 0);
        }
#pragma unroll
        for (int j = 0; j < 4; ++j) {
            va0 = fmaf((float)af[j],     wvp[kk + j],     va0);
            va1 = fmaf((float)af[j + 4], wvp[kk + j + 4], va1);
        }
    }
#pragma unroll
    for (int a = 0; a < 4; ++a)
#pragma unroll
        for (int r = 0; r < 4; ++r)
            lg[w][fhi * 4 + r][a * 16 + fl15] = acc[a][r];
    float va = va0 + va1;
    va += __shfl_xor(va, 16);
    va += __shfl_xor(va, 32);
    if (lane < 16) vpart[w][lane] = va;
    __syncthreads();

    const float bav = ba[lane];
#pragma unroll
    for (int i = 0; i < 2; ++i) {
        const int row = w * 2 + i;
        float logit = bav;
#pragma unroll
        for (int p = 0; p < 8; ++p)
            logit += lg[p][row][lane];
        float m = logit;
#pragma unroll
        for (int mask = 32; mask >= 1; mask >>= 1)
            m = fmaxf(m, __shfl_xor(m, mask));
        const float e = __expf(logit - m);
        float ssum = e;
#pragma unroll
        for (int mask = 32; mask >= 1; mask >>= 1)
            ssum += __shfl_xor(ssum, mask);
        probs[(size_t)(r0 + row) * 64 + lane] = e / ssum;
    }
    if (t < 16) {
        float v = bv[0];
#pragma unroll
        for (int p = 0; p < 8; ++p)
            v += vpart[p][t];
        vout[r0 + t] = v;
    }
}

// ---------------------------------------------------------------------------
extern "C" void kernel_launch(void* const* d_in, const int* in_sizes, int n_in,
                              void* d_out, int out_size, void* d_ws,
                              size_t ws_size, hipStream_t stream)
{
    const float* s      = (const float*)d_in[0];
    const float* a_prev = (const float*)d_in[1];
    const float* r_prev = (const float*)d_in[2];
    const float* h      = (const float*)d_in[3];
    const float* c      = (const float*)d_in[4];
    const float* Wx     = (const float*)d_in[5];
    const float* Wh     = (const float*)d_in[6];
    const float* bh     = (const float*)d_in[7];
    const float* Wa     = (const float*)d_in[8];
    const float* ba     = (const float*)d_in[9];
    const float* Wv     = (const float*)d_in[10];
    const float* bv     = (const float*)d_in[11];

    float* out   = (float*)d_out;
    float* probs = out;                        // [4096*64]
    float* vout  = out + (size_t)BATCH * ADIM; // [4096]

    // Workspace layout (16B-aligned)
    char* ws = (char*)d_ws;
    __hip_bfloat16* xb   = (__hip_bfloat16*)ws;                 //  5,242,880
    __hip_bfloat16* wxt  = (__hip_bfloat16*)(ws + 5242880);     // 10,485,760
    __hip_bfloat16* waT  = (__hip_bfloat16*)(ws + 15728640);    //    262,144
    float* zh_w          = (float*)(ws + 15990784);             //    262,144
    __hip_bfloat16* hnew = (__hip_bfloat16*)(ws + 16252928);    // 16,777,216
    // total 33,030,144 bytes

    setup_kernel<<<5760, 256, 0, stream>>>(
        s, a_prev, r_prev, h, Wx, Wh, Wa, xb, wxt, waT, zh_w);
    lstm_gemm<<<dim3(BATCH / 128, HDIM / 32), 256, 0, stream>>>(
        xb, wxt, zh_w, bh, c, hnew);
    head_kernel<<<BATCH / 16, 512, 0, stream>>>(
        hnew, waT, Wv, ba, bv, probs, vout);
}

// Round 10
// 212.668 us; speedup vs baseline: 1.1402x; 1.1402x over previous
//
#include <hip/hip_runtime.h>
#include <hip/hip_bf16.h>

// Problem constants
#define BATCH   4096
#define SDIM    512
#define ADIM    64
#define IDIM    577           // 512 + 64 + 1
#define KP2     640           // IDIM padded to 10*64
#define NKT64   10            // K-tiles of 64
#define HDIM    2048
#define ZDIM    8192          // 4*HDIM
#define BUFE    (128 * 64)    // LDS elems per buffer (16KB)

typedef __attribute__((ext_vector_type(8))) __bf16 bf16x8;
typedef __attribute__((ext_vector_type(4))) float  accx4;

// ---------------------------------------------------------------------------
// Fused setup kernel (unchanged — proven). Role by flat blockIdx:
//   [0,1280)     transpose Wx: 64k x 64n tiles -> wxt [8192][640]bf16
//   [1280,1536)  zh partials: zh_w[ky][n] = sum_{k in ky*256..+256} h*Wh
//   [1536,5632)  prep xb rows: bf16 [s|a|r|0pad] (4096 x 640)
//   [5632,5760)  transpose Wa [2048,64]f32 -> waT [64][2048]bf16
// ---------------------------------------------------------------------------
__global__ __launch_bounds__(256) void setup_kernel(
    const float* __restrict__ s, const float* __restrict__ a_prev,
    const float* __restrict__ r_prev, const float* __restrict__ h,
    const float* __restrict__ wx, const float* __restrict__ wh,
    const float* __restrict__ wa,
    __hip_bfloat16* __restrict__ xb, __hip_bfloat16* __restrict__ wxt,
    __hip_bfloat16* __restrict__ waT, float* __restrict__ zh_w)
{
    __shared__ float stile[64 * 65];        // 16.6KB, stride 65 (conflict-free)
    const int bid = blockIdx.x;
    const int t = threadIdx.x;

    if (bid < 1280) {                       // ---- transpose Wx (64k x 64n)
        const int kt2 = bid >> 7;           // 0..9
        const int nt  = bid & 127;          // 0..127
        const int c4  = t & 15;             // float4 column
        const int rr  = t >> 4;             // 0..15
#pragma unroll
        for (int i = 0; i < 4; ++i) {
            const int r = rr + i * 16;      // k within tile
            const int k = kt2 * 64 + r;
            float4 v = (k < IDIM)
                ? *(const float4*)(wx + (size_t)k * ZDIM + nt * 64 + c4 * 4)
                : float4{0.f, 0.f, 0.f, 0.f};
            *(float4*)(stile + r * 65 + c4 * 4) = v;
        }
        __syncthreads();
        const int ch = t & 7;               // k-chunk
#pragma unroll
        for (int i = 0; i < 2; ++i) {
            const int nr = (t >> 3) + i * 32;   // n-row 0..63
            bf16x8 w8;
#pragma unroll
            for (int j = 0; j < 8; ++j)
                w8[j] = (__bf16)stile[(ch * 8 + j) * 65 + nr];
            *(bf16x8*)(wxt + (size_t)(nt * 64 + nr) * KP2 + kt2 * 64 + ch * 8)
                = w8;
        }
    } else if (bid < 1536) {                // ---- zh partials (8 k-splits)
        const int zb = bid - 1280;
        const int nb = zb & 31, ky = zb >> 5;       // nb 0..31, ky 0..7
        const int n  = nb * 256 + t;
        const float* hp  = h + ky * 256;
        const float* whp = wh + (size_t)ky * 256 * ZDIM + n;
        float p = 0.0f;
#pragma unroll 16
        for (int kk = 0; kk < 256; ++kk)
            p = fmaf(hp[kk], whp[(size_t)kk * ZDIM], p);
        zh_w[ky * ZDIM + n] = p;
    } else if (bid < 5632) {                // ---- prep xb row
        const int row = bid - 1536;
        const float* srow = s + (size_t)row * SDIM;
        const float* arow = a_prev + (size_t)row * ADIM;
        __hip_bfloat16* xrow = xb + (size_t)row * KP2;
        for (int c = t; c < KP2; c += 256) {
            float v;
            if (c < SDIM)        v = srow[c];
            else if (c < 576)    v = arow[c - SDIM];
            else if (c == 576)   v = r_prev[row];
            else                 v = 0.0f;
            xrow[c] = __float2bfloat16(v);
        }
    } else {                                // ---- transpose Wa (32k x 32a)
        const int wb = bid - 5632;
        const int kt = wb >> 1, at = wb & 1;
        const int c  = t & 31, r0 = t >> 5;
#pragma unroll
        for (int i = 0; i < 4; ++i) {
            int r = r0 + i * 8;             // k within tile
            stile[r * 33 + c] = wa[(size_t)(kt * 32 + r) * ADIM + at * 32 + c];
        }
        __syncthreads();
#pragma unroll
        for (int i = 0; i < 4; ++i) {
            int r = r0 + i * 8;             // action within tile
            waT[(size_t)(at * 32 + r) * HDIM + kt * 32 + c] =
                __float2bfloat16(stile[c * 33 + r]);
        }
    }
}

// ---------------------------------------------------------------------------
// Main bf16 MFMA GEMM + fused LSTM epilogue — the R5/R7 PROVEN structure,
// verbatim: A and B both double-buffered in LDS via global_load_lds
// (BK=64, 128B LDS rows, slot = chunk ^ (row&7) swizzle: HW-verified
// 0 conflicts; one barrier per K-tile; prefetch of tile kt+1 issued before
// compute of tile kt). R9's B-direct-to-register variant regressed 1.65x
// (compiler sinks the loads; full latency exposure) — do not repeat.
// Epilogue folds bh + 8 zh partials (R9-proven) so no zh_reduce launch.
// ---------------------------------------------------------------------------
__device__ __forceinline__ float sigmoid_f(float x) {
    return 1.0f / (1.0f + __expf(-x));
}
__device__ __forceinline__ float tanh_f(float x) {
    return 1.0f - 2.0f / (1.0f + __expf(2.0f * x));
}

__global__ __launch_bounds__(256, 2) void lstm_gemm(
    const __hip_bfloat16* __restrict__ xb,   // [4096][640] bf16
    const __hip_bfloat16* __restrict__ wxt,  // [8192][640] bf16 (n-major)
    const float* __restrict__ zh_w,          // [8][8192] k-split partials
    const float* __restrict__ bh,            // [8192]
    const float* __restrict__ cvec,          // [2048]
    __hip_bfloat16* __restrict__ hout)       // [4096][2048] bf16
{
    __shared__ __bf16 smA[2 * BUFE];   // 32KB  [buf][row][k-chunk swizzled]
    __shared__ __bf16 smB[2 * BUFE];   // 32KB  [buf][zcol][k-chunk swizzled]
    const int t    = threadIdx.x;
    const int lane = t & 63;
    const int wid  = t >> 6;
    const int m0   = blockIdx.x * 128;
    const int n0   = blockIdx.y * 32;
    const int wm   = wid >> 1, wn = wid & 1;
    const int fl15 = lane & 15;
    const int fhi  = lane >> 4;        // 0..3

    accx4 acc[4][4] = {};              // [gate][rowtile]

    // ---- staging addresses (loop-invariant) ----
    const int srow = lane >> 3;        // 0..7
    const int slot = lane & 7;
    const int cch  = slot ^ srow;      // swizzled source chunk (lane-const)
    const __bf16* gA[4]; const __bf16* gB[4]; int lofs[4];
#pragma unroll
    for (int i = 0; i < 4; ++i) {
        const int r = wid * 32 + i * 8 + srow;               // 0..127
        gA[i] = (const __bf16*)xb + (size_t)(m0 + r) * KP2 + cch * 8;
        const int g = r >> 5, nn = r & 31;
        gB[i] = (const __bf16*)wxt +
                (size_t)(g * HDIM + n0 + nn) * KP2 + cch * 8;
        lofs[i] = (wid * 32 + i * 8) * 64;                   // wave-uniform
    }

    auto stage = [&](int tile, int p) {
        const int ko = tile * 64;
        const int po = p * BUFE;
#pragma unroll
        for (int i = 0; i < 4; ++i) {
            __builtin_amdgcn_global_load_lds(
                (const __attribute__((address_space(1))) void*)(gA[i] + ko),
                (__attribute__((address_space(3))) void*)(smA + po + lofs[i]),
                16, 0, 0);
            __builtin_amdgcn_global_load_lds(
                (const __attribute__((address_space(1))) void*)(gB[i] + ko),
                (__attribute__((address_space(3))) void*)(smB + po + lofs[i]),
                16, 0, 0);
        }
    };

    auto compute = [&](int p) {
        const int po = p * BUFE;
#pragma unroll
        for (int hf = 0; hf < 2; ++hf) {
            const int ck = hf * 4 + fhi;                     // wanted chunk
            const int sl = (ck ^ (fl15 & 7)) * 8;            // de-swizzle
            bf16x8 af[4], bfr[4];
#pragma unroll
            for (int rt = 0; rt < 4; ++rt)
                af[rt] = *(const bf16x8*)(smA + po +
                    (wm * 64 + rt * 16 + fl15) * 64 + sl);
#pragma unroll
            for (int g = 0; g < 4; ++g)
                bfr[g] = *(const bf16x8*)(smB + po +
                    (g * 32 + wn * 16 + fl15) * 64 + sl);
#pragma unroll
            for (int g = 0; g < 4; ++g)
#pragma unroll
                for (int rt = 0; rt < 4; ++rt)
                    acc[g][rt] = __builtin_amdgcn_mfma_f32_16x16x32_bf16(
                        af[rt], bfr[g], acc[g][rt], 0, 0, 0);
        }
    };

    stage(0, 0);
    __syncthreads();                   // tile 0 landed (vmcnt drain)
#pragma unroll
    for (int kt = 0; kt < NKT64 - 1; ++kt) {
        stage(kt + 1, (kt + 1) & 1);   // issue next tile FIRST
        compute(kt & 1);               // overlap latency with MFMAs
        __syncthreads();
    }
    compute((NKT64 - 1) & 1);          // last tile, no barrier needed

    // Epilogue. C/D layout: col=lane&15, row=(lane>>4)*4+reg (m89/m91).
    // zh partial-sum folded in (R9-proven): 4 gates x (bh + 8 partials).
    const int colg = n0 + wn * 16 + fl15;        // h-unit index
    float zsum[4];
#pragma unroll
    for (int g = 0; g < 4; ++g) {
        float z = bh[g * HDIM + colg];
#pragma unroll
        for (int j = 0; j < 8; ++j)
            z += zh_w[j * ZDIM + g * HDIM + colg];
        zsum[g] = z;
    }
    const float cv = cvec[colg];
#pragma unroll
    for (int rt = 0; rt < 4; ++rt) {
#pragma unroll
        for (int r = 0; r < 4; ++r) {
            const int row = m0 + wm * 64 + rt * 16 + (fhi << 2) + r;
            const float zi = acc[0][rt][r] + zsum[0];
            const float zf = acc[1][rt][r] + zsum[1];
            const float zg = acc[2][rt][r] + zsum[2];
            const float zo = acc[3][rt][r] + zsum[3];
            const float cn = sigmoid_f(zf) * cv + sigmoid_f(zi) * tanh_f(zg);
            const float hn = sigmoid_f(zo) * tanh_f(cn);
            hout[(size_t)row * HDIM + colg] = __float2bfloat16(hn);
        }
    }
}

// ---------------------------------------------------------------------------
// Policy+value head v3 (unchanged — proven). Block = 16 rows, 512 threads.
// ---------------------------------------------------------------------------
__global__ __launch_bounds__(512) void head_kernel(
    const __hip_bfloat16* __restrict__ hnew,  // [4096][2048] bf16
    const __hip_bfloat16* __restrict__ waT,   // [64][2048] bf16
    const float* __restrict__ wv,             // [2048] f32
    const float* __restrict__ ba, const float* __restrict__ bv,
    float* __restrict__ probs, float* __restrict__ vout)
{
    __shared__ float lg[8][16][68];    // 34.8KB partial logits
    __shared__ float vpart[8][16];
    const int t    = threadIdx.x;
    const int lane = t & 63;
    const int w    = t >> 6;           // k-eighth 0..7
    const int r0   = blockIdx.x * 16;
    const int fl15 = lane & 15, fhi = lane >> 4;
    const int k0   = w * 256;

    const __bf16* arow = (const __bf16*)hnew +
        (size_t)(r0 + fl15) * HDIM + k0 + fhi * 8;
    const __bf16* brow = (const __bf16*)waT +
        (size_t)fl15 * HDIM + k0 + fhi * 8;
    const float* wvp = wv + k0 + fhi * 8;

    accx4 acc[4] = {};
    float va0 = 0.f, va1 = 0.f;
#pragma unroll
    for (int kk = 0; kk < 256; kk += 32) {
        bf16x8 af = *(const bf16x8*)(arow + kk);
#pragma unroll
        for (int a = 0; a < 4; ++a) {
            bf16x8 bf = *(const bf16x8*)(brow + (size_t)a * 16 * HDIM + kk);
            acc[a] = __builtin_amdgcn_mfma_f32_16x16x32_bf16(
                af, bf, acc[a], 0, 0, 0);
        }
#pragma unroll
        for (int j = 0; j < 4; ++j) {
            va0 = fmaf((float)af[j],     wvp[kk + j],     va0);
            va1 = fmaf((float)af[j + 4], wvp[kk + j + 4], va1);
        }
    }
#pragma unroll
    for (int a = 0; a < 4; ++a)
#pragma unroll
        for (int r = 0; r < 4; ++r)
            lg[w][fhi * 4 + r][a * 16 + fl15] = acc[a][r];
    float va = va0 + va1;
    va += __shfl_xor(va, 16);
    va += __shfl_xor(va, 32);
    if (lane < 16) vpart[w][lane] = va;
    __syncthreads();

    const float bav = ba[lane];
#pragma unroll
    for (int i = 0; i < 2; ++i) {
        const int row = w * 2 + i;
        float logit = bav;
#pragma unroll
        for (int p = 0; p < 8; ++p)
            logit += lg[p][row][lane];
        float m = logit;
#pragma unroll
        for (int mask = 32; mask >= 1; mask >>= 1)
            m = fmaxf(m, __shfl_xor(m, mask));
        const float e = __expf(logit - m);
        float ssum = e;
#pragma unroll
        for (int mask = 32; mask >= 1; mask >>= 1)
            ssum += __shfl_xor(ssum, mask);
        probs[(size_t)(r0 + row) * 64 + lane] = e / ssum;
    }
    if (t < 16) {
        float v = bv[0];
#pragma unroll
        for (int p = 0; p < 8; ++p)
            v += vpart[p][t];
        vout[r0 + t] = v;
    }
}

// ---------------------------------------------------------------------------
extern "C" void kernel_launch(void* const* d_in, const int* in_sizes, int n_in,
                              void* d_out, int out_size, void* d_ws,
                              size_t ws_size, hipStream_t stream)
{
    const float* s      = (const float*)d_in[0];
    const float* a_prev = (const float*)d_in[1];
    const float* r_prev = (const float*)d_in[2];
    const float* h      = (const float*)d_in[3];
    const float* c      = (const float*)d_in[4];
    const float* Wx     = (const float*)d_in[5];
    const float* Wh     = (const float*)d_in[6];
    const float* bh     = (const float*)d_in[7];
    const float* Wa     = (const float*)d_in[8];
    const float* ba     = (const float*)d_in[9];
    const float* Wv     = (const float*)d_in[10];
    const float* bv     = (const float*)d_in[11];

    float* out   = (float*)d_out;
    float* probs = out;                        // [4096*64]
    float* vout  = out + (size_t)BATCH * ADIM; // [4096]

    // Workspace layout (16B-aligned)
    char* ws = (char*)d_ws;
    __hip_bfloat16* xb   = (__hip_bfloat16*)ws;                 //  5,242,880
    __hip_bfloat16* wxt  = (__hip_bfloat16*)(ws + 5242880);     // 10,485,760
    __hip_bfloat16* waT  = (__hip_bfloat16*)(ws + 15728640);    //    262,144
    float* zh_w          = (float*)(ws + 15990784);             //    262,144
    __hip_bfloat16* hnew = (__hip_bfloat16*)(ws + 16252928);    // 16,777,216
    // total 33,030,144 bytes

    setup_kernel<<<5760, 256, 0, stream>>>(
        s, a_prev, r_prev, h, Wx, Wh, Wa, xb, wxt, waT, zh_w);
    lstm_gemm<<<dim3(BATCH / 128, HDIM / 32), 256, 0, stream>>>(
        xb, wxt, zh_w, bh, c, hnew);
    head_kernel<<<BATCH / 16, 512, 0, stream>>>(
        hnew, waT, Wv, ba, bv, probs, vout);
}

// Round 11
// 204.621 us; speedup vs baseline: 1.1850x; 1.0393x over previous
//
#include <hip/hip_runtime.h>
#include <hip/hip_bf16.h>

// Problem constants
#define BATCH   4096
#define SDIM    512
#define ADIM    64
#define IDIM    577           // 512 + 64 + 1
#define KP2     576           // GEMM K = s+a exactly (9*64); r handled rank-1
#define NKT64   9             // K-tiles of 64
#define HDIM    2048
#define ZDIM    8192          // 4*HDIM
#define BUFE    (128 * 64)    // LDS elems per buffer (16KB)

typedef __attribute__((ext_vector_type(8))) __bf16 bf16x8;
typedef __attribute__((ext_vector_type(4))) float  accx4;

// ---------------------------------------------------------------------------
// Fused setup kernel. Role by flat blockIdx:
//   [0,1152)     transpose Wx rows 0..575: 64k x 64n tiles -> wxt [8192][576]
//   [1152,1664)  zh partials (16 k-splits): zh_w[ky][n] = sum h*Wh
//   [1664,5760)  prep xb rows: bf16 [s|a] (4096 x 576) — no r, no padding
//   [5760,5888)  transpose Wa [2048,64]f32 -> waT [64][2048]bf16
// ---------------------------------------------------------------------------
__global__ __launch_bounds__(256) void setup_kernel(
    const float* __restrict__ s, const float* __restrict__ a_prev,
    const float* __restrict__ h,
    const float* __restrict__ wx, const float* __restrict__ wh,
    const float* __restrict__ wa,
    __hip_bfloat16* __restrict__ xb, __hip_bfloat16* __restrict__ wxt,
    __hip_bfloat16* __restrict__ waT, float* __restrict__ zh_w)
{
    __shared__ float stile[64 * 65];        // 16.6KB, stride 65 (conflict-free)
    const int bid = blockIdx.x;
    const int t = threadIdx.x;

    if (bid < 1152) {                       // ---- transpose Wx (64k x 64n)
        const int kt2 = bid >> 7;           // 0..8
        const int nt  = bid & 127;          // 0..127
        const int c4  = t & 15;             // float4 column
        const int rr  = t >> 4;             // 0..15
#pragma unroll
        for (int i = 0; i < 4; ++i) {
            const int r = rr + i * 16;      // k within tile (k < 576 < 577)
            const int k = kt2 * 64 + r;
            float4 v =
                *(const float4*)(wx + (size_t)k * ZDIM + nt * 64 + c4 * 4);
            *(float4*)(stile + r * 65 + c4 * 4) = v;
        }
        __syncthreads();
        const int ch = t & 7;               // k-chunk
#pragma unroll
        for (int i = 0; i < 2; ++i) {
            const int nr = (t >> 3) + i * 32;   // n-row 0..63
            bf16x8 w8;
#pragma unroll
            for (int j = 0; j < 8; ++j)
                w8[j] = (__bf16)stile[(ch * 8 + j) * 65 + nr];
            *(bf16x8*)(wxt + (size_t)(nt * 64 + nr) * KP2 + kt2 * 64 + ch * 8)
                = w8;
        }
    } else if (bid < 1664) {                // ---- zh partials (16 k-splits)
        const int zb = bid - 1152;
        const int nb = zb & 31, ky = zb >> 5;       // nb 0..31, ky 0..15
        const int n  = nb * 256 + t;
        const float* hp  = h + ky * 128;
        const float* whp = wh + (size_t)ky * 128 * ZDIM + n;
        float p = 0.0f;
#pragma unroll 32
        for (int kk = 0; kk < 128; ++kk)
            p = fmaf(hp[kk], whp[(size_t)kk * ZDIM], p);
        zh_w[ky * ZDIM + n] = p;
    } else if (bid < 5760) {                // ---- prep xb row (s|a only)
        const int row = bid - 1664;
        const float* srow = s + (size_t)row * SDIM;
        const float* arow = a_prev + (size_t)row * ADIM;
        __hip_bfloat16* xrow = xb + (size_t)row * KP2;
        for (int c = t; c < KP2; c += 256) {
            const float v = (c < SDIM) ? srow[c] : arow[c - SDIM];
            xrow[c] = __float2bfloat16(v);
        }
    } else {                                // ---- transpose Wa (32k x 32a)
        const int wb = bid - 5760;
        const int kt = wb >> 1, at = wb & 1;
        const int c  = t & 31, r0 = t >> 5;
#pragma unroll
        for (int i = 0; i < 4; ++i) {
            int r = r0 + i * 8;             // k within tile
            stile[r * 33 + c] = wa[(size_t)(kt * 32 + r) * ADIM + at * 32 + c];
        }
        __syncthreads();
#pragma unroll
        for (int i = 0; i < 4; ++i) {
            int r = r0 + i * 8;             // action within tile
            waT[(size_t)(at * 32 + r) * HDIM + kt * 32 + c] =
                __float2bfloat16(stile[c * 33 + r]);
        }
    }
}

// ---------------------------------------------------------------------------
// Main bf16 MFMA GEMM + fused LSTM epilogue — R5/R7 PROVEN skeleton
// (A+B LDS double-buffered via global_load_lds, BK=64, 128B LDS rows,
// slot = chunk ^ (row&7) swizzle: HW-verified 0 conflicts; one barrier per
// K-tile; prefetch issued before compute). Changes vs R10 (additive only):
//  * K = 576 exactly (9 tiles, no zero-padding): the r_prev column is a
//    rank-1 update applied in the epilogue (z += r_prev[row]*Wx[576][zcol]).
//  * Epilogue sigmoid/tanh use __builtin_amdgcn_rcpf (v_rcp_f32, 1 instr)
//    instead of IEEE divides (~8 instrs each, no fast-math) — both forms
//    are saturation-stable.
//  * zh = bh + 16 k-split partials (R4-proven count).
// ---------------------------------------------------------------------------
__device__ __forceinline__ float rcp_f(float x) {
    return __builtin_amdgcn_rcpf(x);
}
__device__ __forceinline__ float sigmoid_f(float x) {
    return rcp_f(1.0f + __expf(-x));          // stable: x->-inf => rcp(inf)=0
}
__device__ __forceinline__ float tanh_f(float x) {
    return 1.0f - 2.0f * rcp_f(1.0f + __expf(2.0f * x)); // stable both ends
}

__global__ __launch_bounds__(256, 2) void lstm_gemm(
    const __hip_bfloat16* __restrict__ xb,   // [4096][576] bf16
    const __hip_bfloat16* __restrict__ wxt,  // [8192][576] bf16 (n-major)
    const float* __restrict__ zh_w,          // [16][8192] k-split partials
    const float* __restrict__ bh,            // [8192]
    const float* __restrict__ cvec,          // [2048]
    const float* __restrict__ wx,            // [577][8192] f32 (row 576 used)
    const float* __restrict__ r_prev,        // [4096]
    __hip_bfloat16* __restrict__ hout)       // [4096][2048] bf16
{
    __shared__ __bf16 smA[2 * BUFE];   // 32KB  [buf][row][k-chunk swizzled]
    __shared__ __bf16 smB[2 * BUFE];   // 32KB  [buf][zcol][k-chunk swizzled]
    const int t    = threadIdx.x;
    const int lane = t & 63;
    const int wid  = t >> 6;
    const int m0   = blockIdx.x * 128;
    const int n0   = blockIdx.y * 32;
    const int wm   = wid >> 1, wn = wid & 1;
    const int fl15 = lane & 15;
    const int fhi  = lane >> 4;        // 0..3

    accx4 acc[4][4] = {};              // [gate][rowtile]

    // ---- staging addresses (loop-invariant) ----
    const int srow = lane >> 3;        // 0..7
    const int slot = lane & 7;
    const int cch  = slot ^ srow;      // swizzled source chunk (lane-const)
    const __bf16* gA[4]; const __bf16* gB[4]; int lofs[4];
#pragma unroll
    for (int i = 0; i < 4; ++i) {
        const int r = wid * 32 + i * 8 + srow;               // 0..127
        gA[i] = (const __bf16*)xb + (size_t)(m0 + r) * KP2 + cch * 8;
        const int g = r >> 5, nn = r & 31;
        gB[i] = (const __bf16*)wxt +
                (size_t)(g * HDIM + n0 + nn) * KP2 + cch * 8;
        lofs[i] = (wid * 32 + i * 8) * 64;                   // wave-uniform
    }

    auto stage = [&](int tile, int p) {
        const int ko = tile * 64;
        const int po = p * BUFE;
#pragma unroll
        for (int i = 0; i < 4; ++i) {
            __builtin_amdgcn_global_load_lds(
                (const __attribute__((address_space(1))) void*)(gA[i] + ko),
                (__attribute__((address_space(3))) void*)(smA + po + lofs[i]),
                16, 0, 0);
            __builtin_amdgcn_global_load_lds(
                (const __attribute__((address_space(1))) void*)(gB[i] + ko),
                (__attribute__((address_space(3))) void*)(smB + po + lofs[i]),
                16, 0, 0);
        }
    };

    auto compute = [&](int p) {
        const int po = p * BUFE;
#pragma unroll
        for (int hf = 0; hf < 2; ++hf) {
            const int ck = hf * 4 + fhi;                     // wanted chunk
            const int sl = (ck ^ (fl15 & 7)) * 8;            // de-swizzle
            bf16x8 af[4], bfr[4];
#pragma unroll
            for (int rt = 0; rt < 4; ++rt)
                af[rt] = *(const bf16x8*)(smA + po +
                    (wm * 64 + rt * 16 + fl15) * 64 + sl);
#pragma unroll
            for (int g = 0; g < 4; ++g)
                bfr[g] = *(const bf16x8*)(smB + po +
                    (g * 32 + wn * 16 + fl15) * 64 + sl);
#pragma unroll
            for (int g = 0; g < 4; ++g)
#pragma unroll
                for (int rt = 0; rt < 4; ++rt)
                    acc[g][rt] = __builtin_amdgcn_mfma_f32_16x16x32_bf16(
                        af[rt], bfr[g], acc[g][rt], 0, 0, 0);
        }
    };

    stage(0, 0);
    __syncthreads();                   // tile 0 landed (vmcnt drain)
#pragma unroll
    for (int kt = 0; kt < NKT64 - 1; ++kt) {
        stage(kt + 1, (kt + 1) & 1);   // issue next tile FIRST
        compute(kt & 1);               // overlap latency with MFMAs
        __syncthreads();
    }
    compute((NKT64 - 1) & 1);          // last tile, no barrier needed

    // Epilogue. C/D layout: col=lane&15, row=(lane>>4)*4+reg (m89/m91).
    const int colg = n0 + wn * 16 + fl15;        // h-unit index
    float zsum[4], wxr[4];
#pragma unroll
    for (int g = 0; g < 4; ++g) {
        float z = bh[g * HDIM + colg];
#pragma unroll
        for (int j = 0; j < 16; ++j)
            z += zh_w[j * ZDIM + g * HDIM + colg];
        zsum[g] = z;
        // rank-1 r column: Wx row 576 (f32, read direct from pristine input)
        wxr[g] = wx[(size_t)576 * ZDIM + g * HDIM + colg];
    }
    const float cv = cvec[colg];
#pragma unroll
    for (int rt = 0; rt < 4; ++rt) {
#pragma unroll
        for (int r = 0; r < 4; ++r) {
            const int row = m0 + wm * 64 + rt * 16 + (fhi << 2) + r;
            const float rv = r_prev[row];
            const float zi = acc[0][rt][r] + zsum[0] + rv * wxr[0];
            const float zf = acc[1][rt][r] + zsum[1] + rv * wxr[1];
            const float zg = acc[2][rt][r] + zsum[2] + rv * wxr[2];
            const float zo = acc[3][rt][r] + zsum[3] + rv * wxr[3];
            const float cn = sigmoid_f(zf) * cv + sigmoid_f(zi) * tanh_f(zg);
            const float hn = sigmoid_f(zo) * tanh_f(cn);
            hout[(size_t)row * HDIM + colg] = __float2bfloat16(hn);
        }
    }
}

// ---------------------------------------------------------------------------
// Policy+value head v3 (unchanged — proven). Block = 16 rows, 512 threads.
// ---------------------------------------------------------------------------
__global__ __launch_bounds__(512) void head_kernel(
    const __hip_bfloat16* __restrict__ hnew,  // [4096][2048] bf16
    const __hip_bfloat16* __restrict__ waT,   // [64][2048] bf16
    const float* __restrict__ wv,             // [2048] f32
    const float* __restrict__ ba, const float* __restrict__ bv,
    float* __restrict__ probs, float* __restrict__ vout)
{
    __shared__ float lg[8][16][68];    // 34.8KB partial logits
    __shared__ float vpart[8][16];
    const int t    = threadIdx.x;
    const int lane = t & 63;
    const int w    = t >> 6;           // k-eighth 0..7
    const int r0   = blockIdx.x * 16;
    const int fl15 = lane & 15, fhi = lane >> 4;
    const int k0   = w * 256;

    const __bf16* arow = (const __bf16*)hnew +
        (size_t)(r0 + fl15) * HDIM + k0 + fhi * 8;
    const __bf16* brow = (const __bf16*)waT +
        (size_t)fl15 * HDIM + k0 + fhi * 8;
    const float* wvp = wv + k0 + fhi * 8;

    accx4 acc[4] = {};
    float va0 = 0.f, va1 = 0.f;
#pragma unroll
    for (int kk = 0; kk < 256; kk += 32) {
        bf16x8 af = *(const bf16x8*)(arow + kk);
#pragma unroll
        for (int a = 0; a < 4; ++a) {
            bf16x8 bf = *(const bf16x8*)(brow + (size_t)a * 16 * HDIM + kk);
            acc[a] = __builtin_amdgcn_mfma_f32_16x16x32_bf16(
                af, bf, acc[a], 0, 0, 0);
        }
#pragma unroll
        for (int j = 0; j < 4; ++j) {
            va0 = fmaf((float)af[j],     wvp[kk + j],     va0);
            va1 = fmaf((float)af[j + 4], wvp[kk + j + 4], va1);
        }
    }
#pragma unroll
    for (int a = 0; a < 4; ++a)
#pragma unroll
        for (int r = 0; r < 4; ++r)
            lg[w][fhi * 4 + r][a * 16 + fl15] = acc[a][r];
    float va = va0 + va1;
    va += __shfl_xor(va, 16);
    va += __shfl_xor(va, 32);
    if (lane < 16) vpart[w][lane] = va;
    __syncthreads();

    const float bav = ba[lane];
#pragma unroll
    for (int i = 0; i < 2; ++i) {
        const int row = w * 2 + i;
        float logit = bav;
#pragma unroll
        for (int p = 0; p < 8; ++p)
            logit += lg[p][row][lane];
        float m = logit;
#pragma unroll
        for (int mask = 32; mask >= 1; mask >>= 1)
            m = fmaxf(m, __shfl_xor(m, mask));
        const float e = __expf(logit - m);
        float ssum = e;
#pragma unroll
        for (int mask = 32; mask >= 1; mask >>= 1)
            ssum += __shfl_xor(ssum, mask);
        probs[(size_t)(r0 + row) * 64 + lane] = e / ssum;
    }
    if (t < 16) {
        float v = bv[0];
#pragma unroll
        for (int p = 0; p < 8; ++p)
            v += vpart[p][t];
        vout[r0 + t] = v;
    }
}

// ---------------------------------------------------------------------------
extern "C" void kernel_launch(void* const* d_in, const int* in_sizes, int n_in,
                              void* d_out, int out_size, void* d_ws,
                              size_t ws_size, hipStream_t stream)
{
    const float* s      = (const float*)d_in[0];
    const float* a_prev = (const float*)d_in[1];
    const float* r_prev = (const float*)d_in[2];
    const float* h      = (const float*)d_in[3];
    const float* c      = (const float*)d_in[4];
    const float* Wx     = (const float*)d_in[5];
    const float* Wh     = (const float*)d_in[6];
    const float* bh     = (const float*)d_in[7];
    const float* Wa     = (const float*)d_in[8];
    const float* ba     = (const float*)d_in[9];
    const float* Wv     = (const float*)d_in[10];
    const float* bv     = (const float*)d_in[11];

    float* out   = (float*)d_out;
    float* probs = out;                        // [4096*64]
    float* vout  = out + (size_t)BATCH * ADIM; // [4096]

    // Workspace layout (16B-aligned)
    char* ws = (char*)d_ws;
    __hip_bfloat16* xb   = (__hip_bfloat16*)ws;                 //  4,718,592
    __hip_bfloat16* wxt  = (__hip_bfloat16*)(ws + 4718592);     //  9,437,184
    __hip_bfloat16* waT  = (__hip_bfloat16*)(ws + 14155776);    //    262,144
    float* zh_w          = (float*)(ws + 14417920);             //    524,288
    __hip_bfloat16* hnew = (__hip_bfloat16*)(ws + 14942208);    // 16,777,216
    // total 31,719,424 bytes

    setup_kernel<<<5888, 256, 0, stream>>>(
        s, a_prev, h, Wx, Wh, Wa, xb, wxt, waT, zh_w);
    lstm_gemm<<<dim3(BATCH / 128, HDIM / 32), 256, 0, stream>>>(
        xb, wxt, zh_w, bh, c, Wx, r_prev, hnew);
    head_kernel<<<BATCH / 16, 512, 0, stream>>>(
        hnew, waT, Wv, ba, bv, probs, vout);
}